// Round 1
// baseline (252.751 us; speedup 1.0000x reference)
//
#include <hip/hip_runtime.h>

// GradeWiseLinear: x (8,2048,128,16) f32, block-diagonal linear over last dim,
// grade dims {1,4,6,4,1}. Memory-bound: 128 MiB in + 128 MiB out, ~43 us floor.
//
// R3: one FULL 16-float row per thread (4 float4s = 64 B).
//   - A row is exactly one grade-block group -> no neighbor chunks needed,
//     no cross-thread data, and NO branch divergence (previous version ran a
//     4-way divergent branch at 25% lane utilization).
//   - 4 global_load_dwordx4 + 4 global_store_dwordx4 per thread at 64-B lane
//     stride; the 4 back-to-back instructions fully consume every cache line
//     (L1 absorbs the stride), so HBM traffic stays at the 256 MiB minimum
//     while load-instruction count per unique byte drops 3x vs me/up/dn.
//   - Weights/biases staged once in LDS; all reads are wave-uniform addresses
//     -> hardware broadcast, zero bank conflicts.
//
// LDS weight layout (unchanged):
// [0]      w0 (1x1)
// [1..16]  w1 (4x4 row-major)
// [17..52] w2 (6x6 row-major)
// [53..68] w3 (4x4 row-major)
// [69]     w4 (1x1)
// [70..85] biases b0|b1|b2|b3|b4

__global__ __launch_bounds__(256) void GradeWiseLinear_kernel(
    const float* __restrict__ x,
    const float* __restrict__ w0, const float* __restrict__ b0,
    const float* __restrict__ w1, const float* __restrict__ b1,
    const float* __restrict__ w2, const float* __restrict__ b2,
    const float* __restrict__ w3, const float* __restrict__ b3,
    const float* __restrict__ w4, const float* __restrict__ b4,
    float* __restrict__ out, int nrows)
{
    __shared__ float s[86];
    {
        int t = threadIdx.x;
        if (t < 86) {
            float v;
            if      (t == 0)  v = w0[0];
            else if (t < 17)  v = w1[t - 1];
            else if (t < 53)  v = w2[t - 17];
            else if (t < 69)  v = w3[t - 53];
            else if (t == 69) v = w4[0];
            else if (t == 70) v = b0[0];
            else if (t < 75)  v = b1[t - 71];
            else if (t < 81)  v = b2[t - 75];
            else if (t < 85)  v = b3[t - 81];
            else              v = b4[0];
            s[t] = v;
        }
    }
    __syncthreads();

    int r = blockIdx.x * 256 + threadIdx.x;
    if (r >= nrows) return;

    const float4* __restrict__ x4 = (const float4*)x;
    float4* __restrict__ o4 = (float4*)out;
    const int base = r * 4;

    // x0..x15 = a.xyzw | p.xyzw | c.xyzw | d.xyzw
    float4 a = x4[base + 0];
    float4 p = x4[base + 1];
    float4 c = x4[base + 2];
    float4 d = x4[base + 3];

    float4 y0, y1, y2, y3;

    // grade 0: out0 = b0 + w0*x0
    y0.x = s[70] + s[0] * a.x;

    // grade 1 (4x4), inputs x1..x4 = a.y a.z a.w p.x
    y0.y = s[71] + s[1]  * a.y + s[2]  * a.z + s[3]  * a.w + s[4]  * p.x;
    y0.z = s[72] + s[5]  * a.y + s[6]  * a.z + s[7]  * a.w + s[8]  * p.x;
    y0.w = s[73] + s[9]  * a.y + s[10] * a.z + s[11] * a.w + s[12] * p.x;
    y1.x = s[74] + s[13] * a.y + s[14] * a.z + s[15] * a.w + s[16] * p.x;

    // grade 2 (6x6), inputs x5..x10 = p.y p.z p.w c.x c.y c.z
    y1.y = s[75] + s[17] * p.y + s[18] * p.z + s[19] * p.w
                 + s[20] * c.x + s[21] * c.y + s[22] * c.z;
    y1.z = s[76] + s[23] * p.y + s[24] * p.z + s[25] * p.w
                 + s[26] * c.x + s[27] * c.y + s[28] * c.z;
    y1.w = s[77] + s[29] * p.y + s[30] * p.z + s[31] * p.w
                 + s[32] * c.x + s[33] * c.y + s[34] * c.z;
    y2.x = s[78] + s[35] * p.y + s[36] * p.z + s[37] * p.w
                 + s[38] * c.x + s[39] * c.y + s[40] * c.z;
    y2.y = s[79] + s[41] * p.y + s[42] * p.z + s[43] * p.w
                 + s[44] * c.x + s[45] * c.y + s[46] * c.z;
    y2.z = s[80] + s[47] * p.y + s[48] * p.z + s[49] * p.w
                 + s[50] * c.x + s[51] * c.y + s[52] * c.z;

    // grade 3 (4x4), inputs x11..x14 = c.w d.x d.y d.z
    y2.w = s[81] + s[53] * c.w + s[54] * d.x + s[55] * d.y + s[56] * d.z;
    y3.x = s[82] + s[57] * c.w + s[58] * d.x + s[59] * d.y + s[60] * d.z;
    y3.y = s[83] + s[61] * c.w + s[62] * d.x + s[63] * d.y + s[64] * d.z;
    y3.z = s[84] + s[65] * c.w + s[66] * d.x + s[67] * d.y + s[68] * d.z;

    // grade 4: out15 = b4 + w4*x15
    y3.w = s[85] + s[69] * d.w;

    o4[base + 0] = y0;
    o4[base + 1] = y1;
    o4[base + 2] = y2;
    o4[base + 3] = y3;
}

extern "C" void kernel_launch(void* const* d_in, const int* in_sizes, int n_in,
                              void* d_out, int out_size, void* d_ws, size_t ws_size,
                              hipStream_t stream) {
    const float* x  = (const float*)d_in[0];
    const float* w0 = (const float*)d_in[1];
    const float* b0 = (const float*)d_in[2];
    const float* w1 = (const float*)d_in[3];
    const float* b1 = (const float*)d_in[4];
    const float* w2 = (const float*)d_in[5];
    const float* b2 = (const float*)d_in[6];
    const float* w3 = (const float*)d_in[7];
    const float* b3 = (const float*)d_in[8];
    const float* w4 = (const float*)d_in[9];
    const float* b4 = (const float*)d_in[10];
    float* out = (float*)d_out;

    int nrows = in_sizes[0] / 16;            // 2,097,152 rows of 16 floats
    int block = 256;
    int grid = (nrows + block - 1) / block;  // 8192

    GradeWiseLinear_kernel<<<grid, block, 0, stream>>>(
        x, w0, b0, w1, b1, w2, b2, w3, b3, w4, b4, out, nrows);
}

// Round 2
// 248.998 us; speedup vs baseline: 1.0151x; 1.0151x over previous
//
#include <hip/hip_runtime.h>

// GradeWiseLinear: x (8,2048,128,16) f32, block-diagonal linear over last dim,
// grade dims {1,4,6,4,1}. Memory-bound: 128 MiB in + 128 MiB out, ~43 us floor.
//
// R4: coalesced global access + LDS transpose tile.
//   R3 (row-per-thread, direct global) hit only 30% of HBM peak: lane stride
//   of 64 B makes every global_load_dwordx4 touch 64 distinct cache lines
//   (4x the request rate of a lane-contiguous access) -> TA/L2 request path
//   saturates at ~2.4 TB/s while VALUBusy is 8.5%.
//   Fix: all global loads/stores are lane-contiguous (perfect 1 KiB/instr
//   coalescing); the row gather/scatter happens in LDS (16 KiB tile, reused
//   in-place for input and output).
//
//   LDS swizzle: logical float4 slot s (row r = s>>2, chunk j = s&3) lives at
//   physical slot (s & ~3) | ((s&3) ^ perm(r)), perm(r) = (r ^ (r>>2)) & 3.
//   - Row read (lane l reads 4 slots of row W+l): consecutive 8 lanes hit all
//     8 bank-groups exactly once -> conflict-free (naive layout is 32-way).
//   - Coalesced write/read (lane l accesses slot S+l): swizzle only permutes
//     slots within a quad among 4 lanes -> bank multiset identical to linear
//     -> conflict-free.
//
// Compute body unchanged from R3 (verified): branch-free 70-FMA row kernel,
// weights/biases broadcast from LDS at wave-uniform addresses.
//
// NOTE: assumes n4 % 1024 == 0 (true here: 8*2048*128*16/4 = 8,388,608 =
// 8192 * 1024), so every block is full and early-return-before-sync is
// whole-block-uniform.

__global__ __launch_bounds__(256) void GradeWiseLinear_kernel(
    const float* __restrict__ x,
    const float* __restrict__ w0, const float* __restrict__ b0,
    const float* __restrict__ w1, const float* __restrict__ b1,
    const float* __restrict__ w2, const float* __restrict__ b2,
    const float* __restrict__ w3, const float* __restrict__ b3,
    const float* __restrict__ w4, const float* __restrict__ b4,
    float* __restrict__ out, int n4)
{
    __shared__ float s[86];
    __shared__ float4 tile[1024];   // 16 KiB transpose tile (in, then out)

    {
        int t = threadIdx.x;
        if (t < 86) {
            float v;
            if      (t == 0)  v = w0[0];
            else if (t < 17)  v = w1[t - 1];
            else if (t < 53)  v = w2[t - 17];
            else if (t < 69)  v = w3[t - 53];
            else if (t == 69) v = w4[0];
            else if (t == 70) v = b0[0];
            else if (t < 75)  v = b1[t - 71];
            else if (t < 81)  v = b2[t - 75];
            else if (t < 85)  v = b3[t - 81];
            else              v = b4[0];
            s[t] = v;
        }
    }

    const int t = threadIdx.x;
    const int blockBase = blockIdx.x * 1024;        // float4 index of tile
    if (blockBase >= n4) return;                    // whole-block uniform

    const float4* __restrict__ x4 = (const float4*)x;
    float4* __restrict__ o4 = (float4*)out;

    // ---- phase 1: coalesced global loads -> swizzled LDS writes ----
    // slot s = t + 256k has r = s>>2 with perm(r) = ((t>>2) ^ (t>>4)) & 3
    // (the +256k parts cancel mod 4), so phys(s) = phys(t) + 256k.
    const int pm1 = ((t >> 2) ^ (t >> 4)) & 3;
    const int phys_t = (t & ~3) | ((t & 3) ^ pm1);

    float4 i0 = x4[blockBase + t];
    float4 i1 = x4[blockBase + t + 256];
    float4 i2 = x4[blockBase + t + 512];
    float4 i3 = x4[blockBase + t + 768];
    tile[phys_t      ] = i0;
    tile[phys_t + 256] = i1;
    tile[phys_t + 512] = i2;
    tile[phys_t + 768] = i3;
    __syncthreads();

    // ---- phase 2: each thread owns row r = t (slots 4t..4t+3, swizzled) ----
    const int pm2 = (t ^ (t >> 2)) & 3;
    const int rb  = t * 4;
    // x0..x15 = a.xyzw | q.xyzw | c.xyzw | d.xyzw
    float4 a = tile[rb + (pm2 ^ 0)];
    float4 q = tile[rb + (pm2 ^ 1)];
    float4 c = tile[rb + (pm2 ^ 2)];
    float4 d = tile[rb + (pm2 ^ 3)];

    float4 y0, y1, y2, y3;

    // grade 0: out0 = b0 + w0*x0
    y0.x = s[70] + s[0] * a.x;

    // grade 1 (4x4), inputs x1..x4 = a.y a.z a.w q.x
    y0.y = s[71] + s[1]  * a.y + s[2]  * a.z + s[3]  * a.w + s[4]  * q.x;
    y0.z = s[72] + s[5]  * a.y + s[6]  * a.z + s[7]  * a.w + s[8]  * q.x;
    y0.w = s[73] + s[9]  * a.y + s[10] * a.z + s[11] * a.w + s[12] * q.x;
    y1.x = s[74] + s[13] * a.y + s[14] * a.z + s[15] * a.w + s[16] * q.x;

    // grade 2 (6x6), inputs x5..x10 = q.y q.z q.w c.x c.y c.z
    y1.y = s[75] + s[17] * q.y + s[18] * q.z + s[19] * q.w
                 + s[20] * c.x + s[21] * c.y + s[22] * c.z;
    y1.z = s[76] + s[23] * q.y + s[24] * q.z + s[25] * q.w
                 + s[26] * c.x + s[27] * c.y + s[28] * c.z;
    y1.w = s[77] + s[29] * q.y + s[30] * q.z + s[31] * q.w
                 + s[32] * c.x + s[33] * c.y + s[34] * c.z;
    y2.x = s[78] + s[35] * q.y + s[36] * q.z + s[37] * q.w
                 + s[38] * c.x + s[39] * c.y + s[40] * c.z;
    y2.y = s[79] + s[41] * q.y + s[42] * q.z + s[43] * q.w
                 + s[44] * c.x + s[45] * c.y + s[46] * c.z;
    y2.z = s[80] + s[47] * q.y + s[48] * q.z + s[49] * q.w
                 + s[50] * c.x + s[51] * c.y + s[52] * c.z;

    // grade 3 (4x4), inputs x11..x14 = c.w d.x d.y d.z
    y2.w = s[81] + s[53] * c.w + s[54] * d.x + s[55] * d.y + s[56] * d.z;
    y3.x = s[82] + s[57] * c.w + s[58] * d.x + s[59] * d.y + s[60] * d.z;
    y3.y = s[83] + s[61] * c.w + s[62] * d.x + s[63] * d.y + s[64] * d.z;
    y3.z = s[84] + s[65] * c.w + s[66] * d.x + s[67] * d.y + s[68] * d.z;

    // grade 4: out15 = b4 + w4*x15
    y3.w = s[85] + s[69] * d.w;

    // write back to the same (thread-private between syncs) slots
    tile[rb + (pm2 ^ 0)] = y0;
    tile[rb + (pm2 ^ 1)] = y1;
    tile[rb + (pm2 ^ 2)] = y2;
    tile[rb + (pm2 ^ 3)] = y3;
    __syncthreads();

    // ---- phase 3: swizzled LDS reads -> coalesced global stores ----
    o4[blockBase + t      ] = tile[phys_t];
    o4[blockBase + t + 256] = tile[phys_t + 256];
    o4[blockBase + t + 512] = tile[phys_t + 512];
    o4[blockBase + t + 768] = tile[phys_t + 768];
}

extern "C" void kernel_launch(void* const* d_in, const int* in_sizes, int n_in,
                              void* d_out, int out_size, void* d_ws, size_t ws_size,
                              hipStream_t stream) {
    const float* x  = (const float*)d_in[0];
    const float* w0 = (const float*)d_in[1];
    const float* b0 = (const float*)d_in[2];
    const float* w1 = (const float*)d_in[3];
    const float* b1 = (const float*)d_in[4];
    const float* w2 = (const float*)d_in[5];
    const float* b2 = (const float*)d_in[6];
    const float* w3 = (const float*)d_in[7];
    const float* b3 = (const float*)d_in[8];
    const float* w4 = (const float*)d_in[9];
    const float* b4 = (const float*)d_in[10];
    float* out = (float*)d_out;

    int n4 = in_sizes[0] / 4;                // 8,388,608 float4 chunks
    int block = 256;
    int grid = (n4 + 1023) / 1024;           // 8192 blocks, 1024 float4s each

    GradeWiseLinear_kernel<<<grid, block, 0, stream>>>(
        x, w0, b0, w1, b1, w2, b2, w3, b3, w4, b4, out, n4);
}

// Round 3
// 246.683 us; speedup vs baseline: 1.0246x; 1.0094x over previous
//
#include <hip/hip_runtime.h>

// GradeWiseLinear: x (8,2048,128,16) f32, block-diagonal linear over last dim,
// grade dims {1,4,6,4,1}. Memory-bound: 128 MiB in + 128 MiB out, ~43 us floor.
//
// R5: PERSISTENT grid-stride waves + in-register quad transpose.
//   R2/R3/R4 (one-shot blocks; coalesced or not; LDS tile or not) ALL pinned
//   at ~80 us / ~2.5 TB/s with VALUBusy ~12% and zero bank conflicts -> the
//   limiter is not access pattern, divergence, or LDS. Remaining invariant:
//   one-shot short-lived blocks whose loads are drained (vmcnt(0)) before any
//   use, killing sustained memory-level parallelism. Fix per Guideline 11:
//   2048 blocks x 256 threads, 16 iterations each, 1-deep load pipeline,
//   NO barriers / NO LDS tile in the loop.
//
//   Row handling: with lane-contiguous float4 loads, a 4-lane quad holds one
//   full 16-float row (lane l&3 = chunk j). Chunk j's outputs need only
//   chunks j-1..j+1, which sit at lanes l^1 / l^3:
//     e1 = shfl_xor(cur,1)  -> chunk j^1
//     e3 = shfl_xor(cur,3)  -> chunk j^3
//   8 shuffle instrs per float4; compute is the verified R3 arithmetic with
//   operands renamed per branch (j=0: a=cur,q=e1 | j=1: a=e1,q=cur,c=e3 |
//   j=2: q=e3,c=cur,d=e1 | j=3: c=e1,d=cur). 4-way divergence costs the wave
//   70 FMA per 16 rows -- ~0.5 instr/cy/CU at full HBM rate, not a limiter.
//
//   Weights/biases: 86-float LDS table, wave-uniform reads (broadcast, free).
//   Assumes n4 % 64 == 0 (true: 8,388,608) so waves never split mid-quad.
//
// LDS weight layout (unchanged):
// [0] w0 | [1..16] w1 | [17..52] w2 | [53..68] w3 | [69] w4 | [70..85] biases

__global__ __launch_bounds__(256) void GradeWiseLinear_kernel(
    const float* __restrict__ x,
    const float* __restrict__ w0, const float* __restrict__ b0,
    const float* __restrict__ w1, const float* __restrict__ b1,
    const float* __restrict__ w2, const float* __restrict__ b2,
    const float* __restrict__ w3, const float* __restrict__ b3,
    const float* __restrict__ w4, const float* __restrict__ b4,
    float* __restrict__ out, int n4)
{
    __shared__ float s[86];
    {
        int t = threadIdx.x;
        if (t < 86) {
            float v;
            if      (t == 0)  v = w0[0];
            else if (t < 17)  v = w1[t - 1];
            else if (t < 53)  v = w2[t - 17];
            else if (t < 69)  v = w3[t - 53];
            else if (t == 69) v = w4[0];
            else if (t == 70) v = b0[0];
            else if (t < 75)  v = b1[t - 71];
            else if (t < 81)  v = b2[t - 75];
            else if (t < 85)  v = b3[t - 81];
            else              v = b4[0];
            s[t] = v;
        }
    }
    __syncthreads();

    const int stride = gridDim.x * 256;
    int g = blockIdx.x * 256 + threadIdx.x;
    if (g >= n4) return;

    const int j = g & 3;                      // constant across iterations
    const float4* __restrict__ x4 = (const float4*)x;
    float4* __restrict__ o4 = (float4*)out;

    float4 cur = x4[g];
    for (;;) {
        // ---- prefetch next iteration (1-deep pipeline, no barrier gates) ----
        int gn = g + stride;
        bool have_next = (gn < n4);           // wave-uniform (n4 % 64 == 0)
        float4 nxt;
        if (have_next) nxt = x4[gn];

        // ---- in-register quad transpose: neighbors at lane^1, lane^3 ----
        float4 e1, e3;
        e1.x = __shfl_xor(cur.x, 1);
        e1.y = __shfl_xor(cur.y, 1);
        e1.z = __shfl_xor(cur.z, 1);
        e1.w = __shfl_xor(cur.w, 1);
        e3.x = __shfl_xor(cur.x, 3);
        e3.y = __shfl_xor(cur.y, 3);
        e3.z = __shfl_xor(cur.z, 3);
        e3.w = __shfl_xor(cur.w, 3);

        float4 y;
        if (j == 0) {
            // a = cur, q = e1
            y.x = s[70] + s[0]  * cur.x;
            y.y = s[71] + s[1]  * cur.y + s[2]  * cur.z + s[3]  * cur.w + s[4]  * e1.x;
            y.z = s[72] + s[5]  * cur.y + s[6]  * cur.z + s[7]  * cur.w + s[8]  * e1.x;
            y.w = s[73] + s[9]  * cur.y + s[10] * cur.z + s[11] * cur.w + s[12] * e1.x;
        } else if (j == 1) {
            // a = e1, q = cur, c = e3
            y.x = s[74] + s[13] * e1.y  + s[14] * e1.z  + s[15] * e1.w  + s[16] * cur.x;
            y.y = s[75] + s[17] * cur.y + s[18] * cur.z + s[19] * cur.w
                        + s[20] * e3.x  + s[21] * e3.y  + s[22] * e3.z;
            y.z = s[76] + s[23] * cur.y + s[24] * cur.z + s[25] * cur.w
                        + s[26] * e3.x  + s[27] * e3.y  + s[28] * e3.z;
            y.w = s[77] + s[29] * cur.y + s[30] * cur.z + s[31] * cur.w
                        + s[32] * e3.x  + s[33] * e3.y  + s[34] * e3.z;
        } else if (j == 2) {
            // q = e3, c = cur, d = e1
            y.x = s[78] + s[35] * e3.y  + s[36] * e3.z  + s[37] * e3.w
                        + s[38] * cur.x + s[39] * cur.y + s[40] * cur.z;
            y.y = s[79] + s[41] * e3.y  + s[42] * e3.z  + s[43] * e3.w
                        + s[44] * cur.x + s[45] * cur.y + s[46] * cur.z;
            y.z = s[80] + s[47] * e3.y  + s[48] * e3.z  + s[49] * e3.w
                        + s[50] * cur.x + s[51] * cur.y + s[52] * cur.z;
            y.w = s[81] + s[53] * cur.w + s[54] * e1.x  + s[55] * e1.y  + s[56] * e1.z;
        } else {
            // c = e1, d = cur
            y.x = s[82] + s[57] * e1.w + s[58] * cur.x + s[59] * cur.y + s[60] * cur.z;
            y.y = s[83] + s[61] * e1.w + s[62] * cur.x + s[63] * cur.y + s[64] * cur.z;
            y.z = s[84] + s[65] * e1.w + s[66] * cur.x + s[67] * cur.y + s[68] * cur.z;
            y.w = s[85] + s[69] * cur.w;
        }

        o4[g] = y;

        if (!have_next) break;
        cur = nxt;
        g = gn;
    }
}

extern "C" void kernel_launch(void* const* d_in, const int* in_sizes, int n_in,
                              void* d_out, int out_size, void* d_ws, size_t ws_size,
                              hipStream_t stream) {
    const float* x  = (const float*)d_in[0];
    const float* w0 = (const float*)d_in[1];
    const float* b0 = (const float*)d_in[2];
    const float* w1 = (const float*)d_in[3];
    const float* b1 = (const float*)d_in[4];
    const float* w2 = (const float*)d_in[5];
    const float* b2 = (const float*)d_in[6];
    const float* w3 = (const float*)d_in[7];
    const float* b3 = (const float*)d_in[8];
    const float* w4 = (const float*)d_in[9];
    const float* b4 = (const float*)d_in[10];
    float* out = (float*)d_out;

    int n4 = in_sizes[0] / 4;                // 8,388,608 float4 chunks
    int block = 256;
    int grid = (n4 + block - 1) / block;
    if (grid > 2048) grid = 2048;            // persistent: 8 blocks/CU, 16 iters

    GradeWiseLinear_kernel<<<grid, block, 0, stream>>>(
        x, w0, b0, w1, b1, w2, b2, w3, b3, w4, b4, out, n4);
}